// Round 2
// baseline (803.623 us; speedup 1.0000x reference)
//
#include <hip/hip_runtime.h>
#include <math.h>

// ---------------------------------------------------------------------------
// PatientDistillation: three losses.
//  out[0] = train_loss (CE over s_logits/labels)
//  out[1] = soft_loss  (KL(batchmean) at temperature T, * T^2)
//  out[2] = distill_loss (sum over rows of k smallest same-label sq dists / D)
//
// Heavy part: dot[i][j] = sf_i . tf_j  (B x B x K, K = S*H = 98304) done as a
// bf16 MFMA GEMM (threshold is 2% relative; bf16 input rounding error on the
// ~2e5-scale sq-dists is ~1e-5 relative). Row norms are fused into the GEMM
// staging loop. Split-K partials + small reduce kernel (atomic fallback).
// ---------------------------------------------------------------------------

#define BM 128
#define BN 128
#define BK 32
#define LPITCH 40   // LDS row pitch in bf16 elems: 80 B -> 16B-aligned b128
                    // reads, lanes 0..15 hit banks (r*20)%32 = 2-way (free)

typedef __attribute__((ext_vector_type(8))) short short8;   // 8 bf16 = 4 VGPR
typedef __attribute__((ext_vector_type(4))) float f32x4;

__device__ inline unsigned pack_bf16(float a, float b) {
    // round-to-nearest-even f32 -> bf16, packed pair
    unsigned ua = __float_as_uint(a), ub = __float_as_uint(b);
    ua = (ua + 0x7fffu + ((ua >> 16) & 1u)) >> 16;
    ub = (ub + 0x7fffu + ((ub >> 16) & 1u)) >> 16;
    return (ua & 0xffffu) | (ub << 16);
}

// ---------------- MFMA GEMM: dot partials + fused row norms ---------------
// grid (B/128, B/128, gz); 256 threads = 4 waves, each wave owns a 64x64
// quadrant as 4x4 tiles of 16x16x32 MFMA.
__global__ __launch_bounds__(256) void gemm_dot_kernel(const float* __restrict__ S,
                                                       const float* __restrict__ T,
                                                       float* __restrict__ part,  // [gz][B*B] or null
                                                       float* __restrict__ dotb,  // atomic fallback
                                                       float* __restrict__ s_nrm,
                                                       float* __restrict__ t_nrm,
                                                       int B, int K, int KC,
                                                       int use_part) {
    __shared__ __align__(16) unsigned short As[BM * LPITCH];
    __shared__ __align__(16) unsigned short Bs[BN * LPITCH];

    const int tid  = threadIdx.x;
    const int i0   = blockIdx.x * BM;
    const int j0   = blockIdx.y * BN;
    const int bz   = blockIdx.z;
    const int kbeg = bz * KC;
    const int kend = (kbeg + KC < K) ? (kbeg + KC) : K;

    const int lane = tid & 63;
    const int wid  = tid >> 6;
    const int wm   = wid >> 1;        // 0..1
    const int wn   = wid & 1;         // 0..1
    const int l15  = lane & 15;
    const int quad = lane >> 4;       // 0..3

    f32x4 acc[4][4] = {};
    float pn_s[4] = {0.f, 0.f, 0.f, 0.f};
    float pn_t[4] = {0.f, 0.f, 0.f, 0.f};

    for (int kb = kbeg; kb < kend; kb += BK) {
        __syncthreads();   // previous iter's frag reads done before overwrite
        // stage 128 rows x 32 k of S and T: f32 -> bf16 -> LDS
        #pragma unroll
        for (int l = 0; l < 4; ++l) {
            const int f   = l * 256 + tid;
            const int row = f >> 3;       // 0..127
            const int kq  = f & 7;        // float4 slot in row
            const int gk  = kb + kq * 4;
            float4 sv = {0.f, 0.f, 0.f, 0.f};
            float4 tv = {0.f, 0.f, 0.f, 0.f};
            const int gi = i0 + row, gj = j0 + row;
            if (gk < K) {
                if (gi < B) sv = *(const float4*)&S[(size_t)gi * K + gk];
                if (gj < B) tv = *(const float4*)&T[(size_t)gj * K + gk];
            }
            pn_s[l] += sv.x * sv.x + sv.y * sv.y + sv.z * sv.z + sv.w * sv.w;
            pn_t[l] += tv.x * tv.x + tv.y * tv.y + tv.z * tv.z + tv.w * tv.w;
            uint2 ps = make_uint2(pack_bf16(sv.x, sv.y), pack_bf16(sv.z, sv.w));
            uint2 pt = make_uint2(pack_bf16(tv.x, tv.y), pack_bf16(tv.z, tv.w));
            *(uint2*)&As[row * LPITCH + kq * 4] = ps;
            *(uint2*)&Bs[row * LPITCH + kq * 4] = pt;
        }
        __syncthreads();

        short8 af[4], bf[4];
        #pragma unroll
        for (int mi = 0; mi < 4; ++mi)
            af[mi] = *(const short8*)&As[(wm * 64 + mi * 16 + l15) * LPITCH + quad * 8];
        #pragma unroll
        for (int ni = 0; ni < 4; ++ni)
            bf[ni] = *(const short8*)&Bs[(wn * 64 + ni * 16 + l15) * LPITCH + quad * 8];
        #pragma unroll
        for (int mi = 0; mi < 4; ++mi)
            #pragma unroll
            for (int ni = 0; ni < 4; ++ni)
                acc[mi][ni] = __builtin_amdgcn_mfma_f32_16x16x32_bf16(
                    af[mi], bf[ni], acc[mi][ni], 0, 0, 0);
    }

    // ---- write dot partials ----
    // C/D layout (16x16x32): col = lane&15, row = (lane>>4)*4 + reg
    if (use_part) {
        float* outp = part + (size_t)bz * B * B;
        #pragma unroll
        for (int mi = 0; mi < 4; ++mi) {
            #pragma unroll
            for (int ni = 0; ni < 4; ++ni) {
                #pragma unroll
                for (int r = 0; r < 4; ++r) {
                    const int ig = i0 + wm * 64 + mi * 16 + quad * 4 + r;
                    const int jg = j0 + wn * 64 + ni * 16 + l15;
                    if (ig < B && jg < B)
                        outp[(size_t)ig * B + jg] = acc[mi][ni][r];
                }
            }
        }
    } else {
        #pragma unroll
        for (int mi = 0; mi < 4; ++mi) {
            #pragma unroll
            for (int ni = 0; ni < 4; ++ni) {
                #pragma unroll
                for (int r = 0; r < 4; ++r) {
                    const int ig = i0 + wm * 64 + mi * 16 + quad * 4 + r;
                    const int jg = j0 + wn * 64 + ni * 16 + l15;
                    if (ig < B && jg < B)
                        atomicAdd(&dotb[(size_t)ig * B + jg], acc[mi][ni][r]);
                }
            }
        }
    }

    // ---- fused norm partials: only the designated block column/row ----
    if (blockIdx.y == 0) {
        #pragma unroll
        for (int l = 0; l < 4; ++l) {
            const int row = (l * 256 + tid) >> 3;
            const int gi = i0 + row;
            if (gi < B) atomicAdd(&s_nrm[gi], pn_s[l]);
        }
    }
    if (blockIdx.x == 0) {
        #pragma unroll
        for (int l = 0; l < 4; ++l) {
            const int row = (l * 256 + tid) >> 3;
            const int gj = j0 + row;
            if (gj < B) atomicAdd(&t_nrm[gj], pn_t[l]);
        }
    }
}

// ---------------- split-K partial reduction -------------------------------
__global__ __launch_bounds__(256) void reduce_kernel(const float* __restrict__ part,
                                                     float* __restrict__ dotb,
                                                     int n, int gz) {
    const int i = blockIdx.x * 256 + threadIdx.x;
    if (i >= n) return;
    float s = 0.f;
    for (int z = 0; z < gz; ++z) s += part[(size_t)z * n + i];
    dotb[i] = s;
}

// ---------------- per-row masked top-k smallest: one wave per row ----------
__global__ __launch_bounds__(256) void topk_kernel(const float* __restrict__ dotb,
                                                   const float* __restrict__ s_nrm,
                                                   const float* __restrict__ t_nrm,
                                                   const int* __restrict__ labels,
                                                   const int* __restrict__ kp,
                                                   float* __restrict__ accum,
                                                   int B) {
    const int row  = blockIdx.x * 4 + (threadIdx.x >> 6);
    const int lane = threadIdx.x & 63;
    if (row >= B) return;
    const int lab = labels[row];
    const float sn = s_nrm[row];

    float v[4];
    #pragma unroll
    for (int q = 0; q < 4; ++q) {
        const int j = q * 64 + lane;
        v[q] = INFINITY;
        if (j < B && labels[j] == lab)
            v[q] = fmaxf(sn + t_nrm[j] - 2.0f * dotb[(size_t)row * B + j], 0.0f);
    }

    const int k = kp[0];
    float sum = 0.0f;
    for (int it = 0; it < k; ++it) {
        float m = fminf(fminf(v[0], v[1]), fminf(v[2], v[3]));
        #pragma unroll
        for (int off = 32; off > 0; off >>= 1)
            m = fminf(m, __shfl_xor(m, off, 64));
        if (isinf(m)) break;      // fewer than k finite candidates
        sum += m;
        // invalidate exactly one instance (lowest lane, lowest q)
        const bool has = (v[0] == m) || (v[1] == m) || (v[2] == m) || (v[3] == m);
        const unsigned long long bal = __ballot(has);
        const int first = __ffsll((unsigned long long)bal) - 1;
        if (lane == first) {
            if      (v[0] == m) v[0] = INFINITY;
            else if (v[1] == m) v[1] = INFINITY;
            else if (v[2] == m) v[2] = INFINITY;
            else                v[3] = INFINITY;
        }
    }
    if (lane == 0) atomicAdd(accum, sum);
}

// ---------------- finalize: CE + KL + scale distill ------------------------
__global__ __launch_bounds__(256) void finalize_kernel(const float* __restrict__ t_logits,
                                                       const float* __restrict__ s_logits,
                                                       const int* __restrict__ labels,
                                                       const int* __restrict__ tp,
                                                       const float* __restrict__ accum,
                                                       float* __restrict__ out,
                                                       int B, int NL, int D) {
    const int tid = threadIdx.x;
    const float Tv = (float)tp[0];
    float ce = 0.0f, kl = 0.0f;

    for (int i = tid; i < B; i += 256) {
        const float* sl = s_logits + (size_t)i * NL;
        const float* tl = t_logits + (size_t)i * NL;
        float mx = -INFINITY;
        for (int c = 0; c < NL; ++c) mx = fmaxf(mx, sl[c]);
        float se = 0.0f;
        for (int c = 0; c < NL; ++c) se += expf(sl[c] - mx);
        float lse = logf(se) + mx;
        ce += lse - sl[labels[i]];

        float mxs = -INFINITY, mxt = -INFINITY;
        for (int c = 0; c < NL; ++c) {
            mxs = fmaxf(mxs, sl[c] / Tv);
            mxt = fmaxf(mxt, tl[c] / Tv);
        }
        float ses = 0.0f, set = 0.0f;
        for (int c = 0; c < NL; ++c) {
            ses += expf(sl[c] / Tv - mxs);
            set += expf(tl[c] / Tv - mxt);
        }
        float lses = logf(ses) + mxs;
        float lset = logf(set) + mxt;
        for (int c = 0; c < NL; ++c) {
            float lst = tl[c] / Tv - lset;
            float ls  = sl[c] / Tv - lses;
            kl += expf(lst) * (lst - ls);
        }
    }

    #pragma unroll
    for (int off = 32; off > 0; off >>= 1) {
        ce += __shfl_down(ce, off, 64);
        kl += __shfl_down(kl, off, 64);
    }
    __shared__ float wce[4], wkl[4];
    if ((tid & 63) == 0) { wce[tid >> 6] = ce; wkl[tid >> 6] = kl; }
    __syncthreads();
    if (tid == 0) {
        float ce_t = wce[0] + wce[1] + wce[2] + wce[3];
        float kl_t = wkl[0] + wkl[1] + wkl[2] + wkl[3];
        out[0] = ce_t / (float)B;
        out[1] = kl_t / (float)B * Tv * Tv;
        out[2] = accum[0] / (float)D;
    }
}

// ---------------------------------------------------------------------------
extern "C" void kernel_launch(void* const* d_in, const int* in_sizes, int n_in,
                              void* d_out, int out_size, void* d_ws, size_t ws_size,
                              hipStream_t stream) {
    const float* t_logits = (const float*)d_in[0];
    const float* s_logits = (const float*)d_in[1];
    const float* t_feat   = (const float*)d_in[2];
    const float* s_feat   = (const float*)d_in[3];
    const int*   labels   = (const int*)d_in[4];
    const int*   kp       = (const int*)d_in[5];
    const int*   tp       = (const int*)d_in[6];
    float* out = (float*)d_out;

    const int B  = in_sizes[4];          // 256
    const int NL = in_sizes[0] / B;      // 2
    const int K  = in_sizes[2] / B;      // S*H = 98304
    const size_t BB = (size_t)B * B;

    float* ws    = (float*)d_ws;
    float* dotb  = ws;                   // B*B
    float* s_nrm = ws + BB;              // B
    float* t_nrm = s_nrm + B;            // B
    float* accum = t_nrm + B;            // 1
    float* part  = accum + 1;            // gz * B*B (if it fits)

    // split-K factor: largest gz <= 128 with K % (gz*BK) == 0 whose partial
    // buffer fits in ws; else fall back to atomicAdd accumulation into dotb.
    const size_t fixedf = BB + 2 * (size_t)B + 1;
    size_t capf = (ws_size / 4 > fixedf) ? (ws_size / 4 - fixedf) : 0;
    int maxgz = (int)((capf / BB < 128) ? capf / BB : 128);
    int gz = 0, use_part = 0;
    for (int g = maxgz; g >= 2; --g)
        if (K % (g * BK) == 0) { gz = g; use_part = 1; break; }
    if (!use_part)
        for (int g = 128; g >= 1; --g)
            if (K % (g * BK) == 0) { gz = g; break; }
    const int KC = K / gz;

    hipMemsetAsync(d_ws, 0, sizeof(float) * fixedf, stream);

    dim3 grid((B + BM - 1) / BM, (B + BN - 1) / BN, gz);
    gemm_dot_kernel<<<grid, 256, 0, stream>>>(s_feat, t_feat, part, dotb,
                                              s_nrm, t_nrm, B, K, KC, use_part);
    if (use_part)
        reduce_kernel<<<((int)BB + 255) / 256, 256, 0, stream>>>(part, dotb, (int)BB, gz);

    topk_kernel<<<(B + 3) / 4, 256, 0, stream>>>(dotb, s_nrm, t_nrm, labels, kp, accum, B);

    finalize_kernel<<<1, 256, 0, stream>>>(t_logits, s_logits, labels, tp, accum,
                                           out, B, NL, K);
}

// Round 3
// 312.082 us; speedup vs baseline: 2.5750x; 2.5750x over previous
//
#include <hip/hip_runtime.h>
#include <math.h>

// ---------------------------------------------------------------------------
// PatientDistillation: three losses.
//  out[0] = train_loss (CE over s_logits/labels)
//  out[1] = soft_loss  (KL(batchmean) at temperature T, * T^2)
//  out[2] = distill_loss (sum over rows of k smallest same-label sq dists / D)
//
// dot[i][j] = sf_i . tf_j as bf16 MFMA split-K GEMM (2% rel threshold; bf16
// input rounding is ~1e-5 rel on these sq-dists). NO device atomics in the
// GEMM (R2 lesson: 2048-way-contended device-scope fp atomics on 256 addrs
// stalled the whole dispatch). Norm partials -> plain stores; all reduction
// + topk + CE/KL fused into one tail kernel with last-block-done pattern.
// ---------------------------------------------------------------------------

#define BM 128
#define BN 128
#define BK 32
#define LPITCH 40   // bf16 elems per LDS row: 80 B pitch -> 16B-aligned b128
                    // frag reads, 2-way bank aliasing (free on CDNA4)

typedef __attribute__((ext_vector_type(8))) short short8;   // 8 bf16 = 4 VGPR
typedef __attribute__((ext_vector_type(4))) float f32x4;

__device__ inline unsigned pack_bf16(float a, float b) {
    // round-to-nearest-even f32 -> bf16, packed pair
    unsigned ua = __float_as_uint(a), ub = __float_as_uint(b);
    ua = (ua + 0x7fffu + ((ua >> 16) & 1u)) >> 16;
    ub = (ub + 0x7fffu + ((ub >> 16) & 1u)) >> 16;
    return (ua & 0xffffu) | (ub << 16);
}

// ---------------- MFMA GEMM: dot partials + norm partials (no atomics) -----
// grid (B/128, B/128, gz); 256 threads = 4 waves; wave owns a 64x64 quadrant
// as 4x4 tiles of 16x16x32 bf16 MFMA. Software-pipelined global loads.
__global__ __launch_bounds__(256) void gemm_dot_kernel(const float* __restrict__ S,
                                                       const float* __restrict__ T,
                                                       float* __restrict__ part,   // [gz][B*B]
                                                       float* __restrict__ spart,  // [gz][B]
                                                       float* __restrict__ tpart,  // [gz][B]
                                                       int B, int K, int KC) {
    __shared__ __align__(16) unsigned short As[BM * LPITCH];
    __shared__ __align__(16) unsigned short Bs[BN * LPITCH];

    const int tid  = threadIdx.x;
    const int i0   = blockIdx.x * BM;
    const int j0   = blockIdx.y * BN;
    const int bz   = blockIdx.z;
    const int kbeg = bz * KC;
    const int kend = kbeg + KC;       // KC chosen so kend <= K, KC % BK == 0

    const int lane = tid & 63;
    const int wid  = tid >> 6;
    const int wm   = wid >> 1;
    const int wn   = wid & 1;
    const int l15  = lane & 15;
    const int quad = lane >> 4;

    // per-thread staging coords: row (per l) fixed, kq fixed
    const int kq4 = (tid & 7) * 4;
    int rowl[4];
    bool vi[4], vj[4];
    const float* pS[4];
    const float* pT[4];
    #pragma unroll
    for (int l = 0; l < 4; ++l) {
        rowl[l] = (l * 256 + tid) >> 3;
        int gi = i0 + rowl[l];
        int gj = j0 + rowl[l];
        vi[l] = gi < B;
        vj[l] = gj < B;
        if (gi >= B) gi = B - 1;   // clamp: duplicate data, outputs discarded
        if (gj >= B) gj = B - 1;
        pS[l] = S + (size_t)gi * K + kq4;
        pT[l] = T + (size_t)gj * K + kq4;
    }

    f32x4 acc[4][4] = {};
    float pn_s[4] = {0.f, 0.f, 0.f, 0.f};
    float pn_t[4] = {0.f, 0.f, 0.f, 0.f};

    float4 sv[4], tv[4];
    #pragma unroll
    for (int l = 0; l < 4; ++l) {
        sv[l] = *(const float4*)(pS[l] + kbeg);
        tv[l] = *(const float4*)(pT[l] + kbeg);
    }

    for (int kb = kbeg; kb < kend; kb += BK) {
        __syncthreads();   // prev iter's frag reads done before LDS overwrite
        #pragma unroll
        for (int l = 0; l < 4; ++l) {
            pn_s[l] += sv[l].x * sv[l].x + sv[l].y * sv[l].y
                     + sv[l].z * sv[l].z + sv[l].w * sv[l].w;
            pn_t[l] += tv[l].x * tv[l].x + tv[l].y * tv[l].y
                     + tv[l].z * tv[l].z + tv[l].w * tv[l].w;
            *(uint2*)&As[rowl[l] * LPITCH + kq4] =
                make_uint2(pack_bf16(sv[l].x, sv[l].y), pack_bf16(sv[l].z, sv[l].w));
            *(uint2*)&Bs[rowl[l] * LPITCH + kq4] =
                make_uint2(pack_bf16(tv[l].x, tv[l].y), pack_bf16(tv[l].z, tv[l].w));
        }
        // prefetch next iter's tiles; in flight across barrier + MFMA phase
        const int kn = kb + BK;
        if (kn < kend) {
            #pragma unroll
            for (int l = 0; l < 4; ++l) {
                sv[l] = *(const float4*)(pS[l] + kn);
                tv[l] = *(const float4*)(pT[l] + kn);
            }
        }
        __syncthreads();

        short8 af[4], bf[4];
        #pragma unroll
        for (int mi = 0; mi < 4; ++mi)
            af[mi] = *(const short8*)&As[(wm * 64 + mi * 16 + l15) * LPITCH + quad * 8];
        #pragma unroll
        for (int ni = 0; ni < 4; ++ni)
            bf[ni] = *(const short8*)&Bs[(wn * 64 + ni * 16 + l15) * LPITCH + quad * 8];
        #pragma unroll
        for (int mi = 0; mi < 4; ++mi)
            #pragma unroll
            for (int ni = 0; ni < 4; ++ni)
                acc[mi][ni] = __builtin_amdgcn_mfma_f32_16x16x32_bf16(
                    af[mi], bf[ni], acc[mi][ni], 0, 0, 0);
    }

    // ---- dot partials: plain stores ----
    // C/D layout (16x16x32): col = lane&15, row = (lane>>4)*4 + reg
    float* outp = part + (size_t)bz * B * B;
    #pragma unroll
    for (int mi = 0; mi < 4; ++mi) {
        #pragma unroll
        for (int ni = 0; ni < 4; ++ni) {
            #pragma unroll
            for (int r = 0; r < 4; ++r) {
                const int ig = i0 + wm * 64 + mi * 16 + quad * 4 + r;
                const int jg = j0 + wn * 64 + ni * 16 + l15;
                if (ig < B && jg < B)
                    outp[(size_t)ig * B + jg] = acc[mi][ni][r];
            }
        }
    }

    // ---- norm partials: 8-lane shuffle reduce, one plain store per row ----
    if (blockIdx.y == 0) {
        #pragma unroll
        for (int l = 0; l < 4; ++l) {
            float v = pn_s[l];
            v += __shfl_xor(v, 1, 64);
            v += __shfl_xor(v, 2, 64);
            v += __shfl_xor(v, 4, 64);
            const int gi = i0 + rowl[l];
            if ((tid & 7) == 0 && vi[l]) spart[(size_t)bz * B + gi] = v;
        }
    }
    if (blockIdx.x == 0) {
        #pragma unroll
        for (int l = 0; l < 4; ++l) {
            float v = pn_t[l];
            v += __shfl_xor(v, 1, 64);
            v += __shfl_xor(v, 2, 64);
            v += __shfl_xor(v, 4, 64);
            const int gj = j0 + rowl[l];
            if ((tid & 7) == 0 && vj[l]) tpart[(size_t)bz * B + gj] = v;
        }
    }
}

// ---------------- tail: reduce partials + topk + CE/KL, one kernel ---------
// grid = B blocks x 256 threads; block i handles output row i. The last
// block to finish (atomic counter) also computes CE/KL and writes out[0..2].
__global__ __launch_bounds__(256) void tail_kernel(const float* __restrict__ part,
                                                   const float* __restrict__ spart,
                                                   const float* __restrict__ tpart,
                                                   const float* __restrict__ t_logits,
                                                   const float* __restrict__ s_logits,
                                                   const int* __restrict__ labels,
                                                   const int* __restrict__ kp,
                                                   const int* __restrict__ tp,
                                                   float* __restrict__ rowsum,
                                                   int* __restrict__ counter,
                                                   float* __restrict__ out,
                                                   int B, int K, int NL, int gz) {
    const int i   = blockIdx.x;
    const int tid = threadIdx.x;
    const size_t BB = (size_t)B * B;

    __shared__ float svals[256];
    __shared__ float rv[256];
    __shared__ int   ri[256];
    __shared__ float red[4];
    __shared__ int   lastf;

    // reduce dot row i and t_nrm column tid across z
    float dt = 0.f, tn = 0.f;
    if (tid < B) {
        for (int z = 0; z < gz; ++z) {
            dt += part[(size_t)z * BB + (size_t)i * B + tid];
            tn += tpart[(size_t)z * B + tid];
        }
    }
    // s_nrm_i: distribute z over threads, block-reduce
    float sp = (tid < gz) ? spart[(size_t)tid * B + i] : 0.f;
    #pragma unroll
    for (int off = 32; off > 0; off >>= 1) sp += __shfl_down(sp, off, 64);
    if ((tid & 63) == 0) red[tid >> 6] = sp;
    __syncthreads();
    const float sn = red[0] + red[1] + red[2] + red[3];

    float v = INFINITY;
    if (tid < B && labels[i] == labels[tid])
        v = fmaxf(sn + tn - 2.0f * dt, 0.0f);
    svals[tid] = v;
    __syncthreads();

    // top-k smallest via LDS tournament
    const int k = kp[0];
    float sum = 0.0f;
    for (int it = 0; it < k; ++it) {
        rv[tid] = svals[tid];
        ri[tid] = tid;
        __syncthreads();
        #pragma unroll
        for (int s = 128; s > 0; s >>= 1) {
            if (tid < s) {
                if (rv[tid + s] < rv[tid]) { rv[tid] = rv[tid + s]; ri[tid] = ri[tid + s]; }
            }
            __syncthreads();
        }
        if (tid == 0) {
            if (rv[0] < 3.0e38f) sum += rv[0];
            svals[ri[0]] = INFINITY;
        }
        __syncthreads();
    }

    if (tid == 0) {
        rowsum[i] = sum;
        __threadfence();
        lastf = (atomicAdd(counter, 1) == B - 1) ? 1 : 0;
    }
    __syncthreads();
    if (!lastf) return;

    // ---- last block: finalize all three losses ----
    __threadfence();
    const float Tv = (float)tp[0];
    float rs = (tid < B) ? rowsum[tid] : 0.f;
    float ce = 0.0f, kl = 0.0f;
    for (int s = tid; s < B; s += 256) {
        const float* sl = s_logits + (size_t)s * NL;
        const float* tl = t_logits + (size_t)s * NL;
        float mx = -INFINITY;
        for (int c = 0; c < NL; ++c) mx = fmaxf(mx, sl[c]);
        float se = 0.0f;
        for (int c = 0; c < NL; ++c) se += expf(sl[c] - mx);
        ce += logf(se) + mx - sl[labels[s]];

        float mxs = -INFINITY, mxt = -INFINITY;
        for (int c = 0; c < NL; ++c) {
            mxs = fmaxf(mxs, sl[c] / Tv);
            mxt = fmaxf(mxt, tl[c] / Tv);
        }
        float ses = 0.0f, set = 0.0f;
        for (int c = 0; c < NL; ++c) {
            ses += expf(sl[c] / Tv - mxs);
            set += expf(tl[c] / Tv - mxt);
        }
        float lses = logf(ses) + mxs;
        float lset = logf(set) + mxt;
        for (int c = 0; c < NL; ++c) {
            float lst = tl[c] / Tv - lset;
            float ls  = sl[c] / Tv - lses;
            kl += expf(lst) * (lst - ls);
        }
    }
    #pragma unroll
    for (int off = 32; off > 0; off >>= 1) {
        ce += __shfl_down(ce, off, 64);
        kl += __shfl_down(kl, off, 64);
        rs += __shfl_down(rs, off, 64);
    }
    __shared__ float wce[4], wkl[4], wrs[4];
    if ((tid & 63) == 0) { wce[tid >> 6] = ce; wkl[tid >> 6] = kl; wrs[tid >> 6] = rs; }
    __syncthreads();
    if (tid == 0) {
        out[0] = (wce[0] + wce[1] + wce[2] + wce[3]) / (float)B;
        out[1] = (wkl[0] + wkl[1] + wkl[2] + wkl[3]) / (float)B * Tv * Tv;
        out[2] = (wrs[0] + wrs[1] + wrs[2] + wrs[3]) / (float)K;
    }
}

// ---------------------------------------------------------------------------
extern "C" void kernel_launch(void* const* d_in, const int* in_sizes, int n_in,
                              void* d_out, int out_size, void* d_ws, size_t ws_size,
                              hipStream_t stream) {
    const float* t_logits = (const float*)d_in[0];
    const float* s_logits = (const float*)d_in[1];
    const float* t_feat   = (const float*)d_in[2];
    const float* s_feat   = (const float*)d_in[3];
    const int*   labels   = (const int*)d_in[4];
    const int*   kp       = (const int*)d_in[5];
    const int*   tp       = (const int*)d_in[6];
    float* out = (float*)d_out;

    const int B  = in_sizes[4];          // 256
    const int NL = in_sizes[0] / B;      // 2
    const int K  = in_sizes[2] / B;      // S*H = 98304
    const size_t BB = (size_t)B * B;

    // split-K: largest gz (<=192 -> 768 blocks = 3/CU) dividing K into
    // BK-multiples whose partials fit in ws.
    const size_t avail = ws_size / 4;
    const int cands[] = {192, 128, 96, 64, 48, 32, 24, 16, 12, 8, 6, 4, 3, 2, 1};
    int gz = 1;
    for (int ci = 0; ci < 15; ++ci) {
        const int g = cands[ci];
        if (K % (g * BK) != 0) continue;
        const size_t need = (size_t)g * BB + 2 * (size_t)g * B + B + 4;
        if (need <= avail) { gz = g; break; }
    }
    const int KC = K / gz;

    float* ws     = (float*)d_ws;
    float* part   = ws;                          // gz * B*B
    float* spart  = part + (size_t)gz * BB;      // gz * B
    float* tpart  = spart + (size_t)gz * B;      // gz * B
    float* rowsum = tpart + (size_t)gz * B;      // B
    int*   counter = (int*)(rowsum + B);         // 1

    hipMemsetAsync(counter, 0, sizeof(int), stream);

    dim3 grid((B + BM - 1) / BM, (B + BN - 1) / BN, gz);
    gemm_dot_kernel<<<grid, 256, 0, stream>>>(s_feat, t_feat, part, spart, tpart,
                                              B, K, KC);

    tail_kernel<<<B, 256, 0, stream>>>(part, spart, tpart, t_logits, s_logits,
                                       labels, kp, tp, rowsum, counter, out,
                                       B, K, NL, gz);
}